// Round 10
// baseline (668.413 us; speedup 1.0000x reference)
//
#include <hip/hip_runtime.h>

#define N_NODES 200000
#define N_EDGES 400000
#define N_GRAPHS 64
#define HDIM 128
#define INDIM 5
#define LN_EPS 1e-5f
#define LDA 140   // 70 dwords/row: 70 mod 32 = 6 -> frag reads distributed
#define NPBLK 128 // nodes per block (4 waves x 32 wave-local rows)
#define NBLKS ((N_NODES + NPBLK - 1) / NPBLK)  // 1563 (last block: 64 valid rows)

typedef __attribute__((ext_vector_type(8))) short short8;
typedef __attribute__((ext_vector_type(4))) float f32x4;
typedef __attribute__((ext_vector_type(2))) float f32x2;

__device__ __forceinline__ unsigned short to_bf(float v) {
    unsigned u = __builtin_bit_cast(unsigned, v);
    return (unsigned short)((u + 0x7FFFu + ((u >> 16) & 1u)) >> 16);
}
__device__ __forceinline__ float bf_lo(unsigned w) { return __builtin_bit_cast(float, w << 16); }
__device__ __forceinline__ float bf_hi(unsigned w) { return __builtin_bit_cast(float, w & 0xFFFF0000u); }
__device__ __forceinline__ float bf2f(unsigned short h) { return __builtin_bit_cast(float, (unsigned)h << 16); }

// 1-instr RTNE f32->bf16 (same rounding as to_bf)
__device__ __forceinline__ unsigned short cvt1_bf(float v) {
    unsigned r;
    asm("v_cvt_pk_bf16_f32 %0, %1, %1" : "=v"(r) : "v"(v));
    return (unsigned short)r;
}
__device__ __forceinline__ unsigned cvt2_bf(float lo, float hi) {
    unsigned r;
    asm("v_cvt_pk_bf16_f32 %0, %1, %2" : "=v"(r) : "v"(lo), "v"(hi));
    return r;
}
__device__ __forceinline__ f32x2 vmax0(f32x2 v) {
#if __has_builtin(__builtin_elementwise_max)
    return __builtin_elementwise_max(v, (f32x2)0.f);
#else
    v.x = fmaxf(v.x, 0.f);
    v.y = fmaxf(v.y, 0.f);
    return v;
#endif
}

// ---- gather macros: 64 ch/thread (32 dwords = 8 uint4). Literal indices only,
// no staging arrays, no pointer-passed locals (R1/R3), no token pasting (R2).
#define GLOAD8(y0, y1, y2, y3, y4, y5, y6, y7, srcrow)                      \
    {                                                                       \
        const uint4* xs_ = (const uint4*)(xin + (size_t)(srcrow)*128 + c0); \
        y0 = xs_[0]; y1 = xs_[1]; y2 = xs_[2]; y3 = xs_[3];                 \
        y4 = xs_[4]; y5 = xs_[5]; y6 = xs_[6]; y7 = xs_[7];                 \
    }

// one dword wd = channel pair (2*i0, 2*i0+1): accv += relu((x + eb) + a*ew), packed f32x2
#define GP2(wd, i0)            \
    {                          \
        float4 wb_ = ep[i0];   \
        f32x2 xv_;             \
        xv_.x = bf_lo(wd);     \
        xv_.y = bf_hi(wd);     \
        f32x2 ew_, eb_;        \
        ew_.x = wb_.x;         \
        ew_.y = wb_.y;         \
        eb_.x = wb_.z;         \
        eb_.y = wb_.w;         \
        f32x2 t_ = xv_ + eb_;  \
        t_ = av2_ * ew_ + t_;  \
        accv[i0] += vmax0(t_); \
    }

#define GPROC8(y0, y1, y2, y3, y4, y5, y6, y7, a_)              \
    {                                                           \
        f32x2 av2_;                                             \
        av2_.x = (a_);                                          \
        av2_.y = (a_);                                          \
        GP2(y0.x, 0) GP2(y0.y, 1) GP2(y0.z, 2) GP2(y0.w, 3)     \
        GP2(y1.x, 4) GP2(y1.y, 5) GP2(y1.z, 6) GP2(y1.w, 7)     \
        GP2(y2.x, 8) GP2(y2.y, 9) GP2(y2.z, 10) GP2(y2.w, 11)   \
        GP2(y3.x, 12) GP2(y3.y, 13) GP2(y3.z, 14) GP2(y3.w, 15) \
        GP2(y4.x, 16) GP2(y4.y, 17) GP2(y4.z, 18) GP2(y4.w, 19) \
        GP2(y5.x, 20) GP2(y5.y, 21) GP2(y5.z, 22) GP2(y5.w, 23) \
        GP2(y6.x, 24) GP2(y6.y, 25) GP2(y6.z, 26) GP2(y6.w, 27) \
        GP2(y7.x, 28) GP2(y7.y, 29) GP2(y7.z, 30) GP2(y7.w, 31) \
    }

#define GI2(wd, i0)             \
    {                           \
        accv[i0].x = bf_lo(wd); \
        accv[i0].y = bf_hi(wd); \
    }

#define GINIT8(y0, y1, y2, y3, y4, y5, y6, y7)                  \
    {                                                           \
        GI2(y0.x, 0) GI2(y0.y, 1) GI2(y0.z, 2) GI2(y0.w, 3)     \
        GI2(y1.x, 4) GI2(y1.y, 5) GI2(y1.z, 6) GI2(y1.w, 7)     \
        GI2(y2.x, 8) GI2(y2.y, 9) GI2(y2.z, 10) GI2(y2.w, 11)   \
        GI2(y3.x, 12) GI2(y3.y, 13) GI2(y3.z, 14) GI2(y3.w, 15) \
        GI2(y4.x, 16) GI2(y4.y, 17) GI2(y4.z, 18) GI2(y4.w, 19) \
        GI2(y5.x, 20) GI2(y5.y, 21) GI2(y5.z, 22) GI2(y5.w, 23) \
        GI2(y6.x, 24) GI2(y6.y, 25) GI2(y6.z, 26) GI2(y6.w, 27) \
        GI2(y7.x, 28) GI2(y7.y, 29) GI2(y7.z, 30) GI2(y7.w, 31) \
    }

// ---------------- CSR build ----------------

__global__ void hist_kernel(const int* __restrict__ ei, int* __restrict__ deg) {
    int e = blockIdx.x * blockDim.x + threadIdx.x;
    if (e < N_EDGES) atomicAdd(&deg[ei[N_EDGES + e]], 1);
}

#define SCAN_CHUNK 1024
#define SCAN_BLOCKS ((N_NODES + SCAN_CHUNK - 1) / SCAN_CHUNK)  // 196

__global__ __launch_bounds__(256) void scan_phaseA(const int* __restrict__ deg, int* __restrict__ bsums,
                                                   int* __restrict__ poolz) {
    if (blockIdx.x == 0) {
        for (int i = threadIdx.x; i < N_GRAPHS * HDIM + N_GRAPHS; i += 256) poolz[i] = 0;
    }
    __shared__ int red[256];
    int t = threadIdx.x;
    int base = blockIdx.x * SCAN_CHUNK + t * 4;
    int s = 0;
#pragma unroll
    for (int k = 0; k < 4; ++k) {
        int i = base + k;
        s += (i < N_NODES) ? deg[i] : 0;
    }
    red[t] = s;
    __syncthreads();
    for (int off = 128; off; off >>= 1) {
        if (t < off) red[t] += red[t + off];
        __syncthreads();
    }
    if (t == 0) bsums[blockIdx.x] = red[0];
}

__global__ __launch_bounds__(256) void scan_phaseB(int* __restrict__ bsums, int* __restrict__ row_ptr) {
    __shared__ int s[256];
    int t = threadIdx.x;
    int v = (t < SCAN_BLOCKS) ? bsums[t] : 0;
    s[t] = v;
    __syncthreads();
    for (int off = 1; off < 256; off <<= 1) {
        int add = (t >= off) ? s[t - off] : 0;
        __syncthreads();
        s[t] += add;
        __syncthreads();
    }
    if (t < SCAN_BLOCKS) bsums[t] = s[t] - v;  // exclusive
    if (t == SCAN_BLOCKS - 1) row_ptr[N_NODES] = s[t];
}

__global__ __launch_bounds__(256) void scan_phaseC(const int* __restrict__ deg,
                                                   const int* __restrict__ bsums,
                                                   int* __restrict__ row_ptr,
                                                   int* __restrict__ cursor) {
    __shared__ int ts[256];
    int t = threadIdx.x;
    int base = blockIdx.x * SCAN_CHUNK + t * 4;
    int v[4];
    int s = 0;
#pragma unroll
    for (int k = 0; k < 4; ++k) {
        int i = base + k;
        v[k] = (i < N_NODES) ? deg[i] : 0;
        s += v[k];
    }
    ts[t] = s;
    __syncthreads();
    for (int off = 1; off < 256; off <<= 1) {
        int add = (t >= off) ? ts[t - off] : 0;
        __syncthreads();
        ts[t] += add;
        __syncthreads();
    }
    int run = bsums[blockIdx.x] + ts[t] - s;
#pragma unroll
    for (int k = 0; k < 4; ++k) {
        int i = base + k;
        if (i < N_NODES) { row_ptr[i] = run; cursor[i] = 0; }
        run += v[k];
    }
}

// ---------------- Fused scatter (CSR fill) + weight packing ----------------
#define SCATTER_BLOCKS ((N_EDGES + 255) / 256)  // 1563

__global__ void scatter_pack(const int* __restrict__ ei, const float* __restrict__ ea,
                             const int* __restrict__ row_ptr, int* __restrict__ cursor,
                             int2* __restrict__ csr,
                             const float* __restrict__ s0, short* __restrict__ d0,
                             const float* __restrict__ s1, short* __restrict__ d1,
                             const float* __restrict__ s2, short* __restrict__ d2,
                             const float* __restrict__ s3, short* __restrict__ d3,
                             const float* __restrict__ s4, short* __restrict__ d4,
                             const float* __restrict__ s5, short* __restrict__ d5) {
    int b = blockIdx.x;
    if (b < SCATTER_BLOCKS) {
        int e = b * 256 + threadIdx.x;
        if (e >= N_EDGES) return;
        int d = ei[N_EDGES + e];
        int pos = atomicAdd(&cursor[d], 1);
        csr[row_ptr[d] + pos] = make_int2(ei[e], __float_as_int(ea[e]));
        return;
    }
    b -= SCATTER_BLOCKS;
    const float* W;
    short* D;
    int din, KP, b0;
    if (b < 16)       { W = s0; D = d0; din = 5;   KP = 32;  b0 = 0; }
    else if (b < 80)  { W = s1; D = d1; din = 128; KP = 128; b0 = 16; }
    else if (b < 144) { W = s2; D = d2; din = 128; KP = 128; b0 = 80; }
    else if (b < 208) { W = s3; D = d3; din = 128; KP = 128; b0 = 144; }
    else if (b < 272) { W = s4; D = d4; din = 128; KP = 128; b0 = 208; }
    else              { W = s5; D = d5; din = 128; KP = 128; b0 = 272; }
    int idx = (b - b0) * 256 + threadIdx.x;
    if (idx >= KP * 128) return;
    int j = idx & 7;
    int lane = (idx >> 3) & 63;
    int rest = idx >> 9;
    int KS = KP >> 5;
    int kstep = rest % KS;
    int tile = rest / KS;
    int k = kstep * 32 + ((lane >> 4) * 8) + j;
    int n = tile * 16 + (lane & 15);
    float v = (k < din) ? W[k * 128 + n] : 0.f;
    D[idx] = (short)to_bf(v);
}

// ---------------- Fused layer: gather + MFMA MLP + reg-LN + ReLU (+pool) ----------------
// NPBLK=128, 256 thr = 4 waves, 32 WAVE-LOCAL rows/wave (no gather<->tail barrier).
// LDS 37.4KB > 32KB caps occupancy at 4 blocks/CU = 4 waves/SIMD -> compiler VGPR
// budget 128 (R3/R4 lesson: with small LDS it targets 8 waves -> 64 VGPR -> spill).
// Tail: 2 row-groups per bh load -> weight traffic per node halved vs R8.
template <int KP1, bool POOL>
__global__ __launch_bounds__(256, 4) void layer_fused(
    const void* __restrict__ xin_v, const int* __restrict__ row_ptr,
    const int2* __restrict__ csr,
    const float* __restrict__ ew, const float* __restrict__ eb,
    const short* __restrict__ w1h, const float* __restrict__ b1,
    const short* __restrict__ w2h, const float* __restrict__ b2,
    const float* __restrict__ g, const float* __restrict__ bt,
    unsigned short* __restrict__ xout,
    const int* __restrict__ batch, float* __restrict__ pool, int* __restrict__ cnt) {
    __shared__ __align__(16) unsigned short A16[NPBLK * LDA];
    __shared__ int bidx[NPBLK];
    union Scratch {
        float4 eweb4[2 * 33];                          // {ew,ew,eb,eb} pairs, half-stride 33 (2-way bcast = free)
        float part[KP1 == 128 ? 1 : NPBLK][2][INDIM];  // layer-0 gather partials
    };
    __shared__ __align__(16) Scratch u;

    int tid = threadIdx.x;
    int node0 = blockIdx.x * NPBLK;

    if constexpr (KP1 == 128) {
        const unsigned short* xin = (const unsigned short*)xin_v;
        // stage padded edge-encoder table
        if (tid < 64) {
            int hh = tid >> 5, ii = tid & 31, c = hh * 64 + ii * 2;
            u.eweb4[hh * 33 + ii] = make_float4(ew[c], ew[c + 1], eb[c], eb[c + 1]);
        }
        if (POOL && tid >= 128) bidx[tid - 128] = batch[min(node0 + tid - 128, N_NODES - 1)];

        // thread = (row, 64-channel half)
        int row = tid >> 1, half = tid & 1, c0 = half * 64;
        int node = min(node0 + row, N_NODES - 1);  // ghost rows (last block) clamp; never stored

        // own-row + pipeline prologue issued before the barrier (in flight across it)
        const uint4* xn = (const uint4*)(xin + (size_t)node * 128 + c0);
        uint4 o0 = xn[0], o1 = xn[1], o2 = xn[2], o3 = xn[3];
        uint4 o4 = xn[4], o5 = xn[5], o6 = xn[6], o7 = xn[7];
        int beg = row_ptr[node], end = row_ptr[node + 1];

        uint4 va0, va1, va2, va3, va4, va5, va6, va7;
        float aA = 0.f;
        int2 rC = make_int2(0, 0), rD = rC;
        if (beg < end) {
            int2 r = csr[beg];
            aA = __int_as_float(r.y);
            GLOAD8(va0, va1, va2, va3, va4, va5, va6, va7, r.x);
        }
        if (beg + 1 < end) rC = csr[beg + 1];
        if (beg + 2 < end) rD = csr[beg + 2];
        __syncthreads();  // eweb4 ready
        const float4* ep = u.eweb4 + half * 33;

        f32x2 accv[32];
        GINIT8(o0, o1, o2, o3, o4, o5, o6, o7);

        // 1-deep x pipeline + distance-2 csr prefetch (R6-proven codegen)
        int e = beg;
        while (e + 1 < end) {
            GPROC8(va0, va1, va2, va3, va4, va5, va6, va7, aA);  // waits this edge's x only
            aA = __int_as_float(rC.y);
            GLOAD8(va0, va1, va2, va3, va4, va5, va6, va7, rC.x);  // rC resident -> no wait
            rC = rD;
            int i3 = min(e + 3, end - 1);  // unconditional clamped (no branch-merge waitcnt)
            rD = csr[i3];
            ++e;
        }
        if (e < end) GPROC8(va0, va1, va2, va3, va4, va5, va6, va7, aA);

        // packed cvt + uint2 stores
        uint2* Ar2 = (uint2*)&A16[row * LDA + c0];
#pragma unroll
        for (int k = 0; k < 16; ++k) {
            Ar2[k] = make_uint2(cvt2_bf(accv[2 * k].x, accv[2 * k].y),
                                cvt2_bf(accv[2 * k + 1].x, accv[2 * k + 1].y));
        }
        // no barrier: rows [32wv, 32wv+32) written and read by the same wave
    } else {
        // layer 0 (din=5): 2 threads/row split the edge list; register partials
        const float* xinf = (const float*)xin_v;
        int row = tid >> 1, qt = tid & 1;
        int node = min(node0 + row, N_NODES - 1);
        {
            float w[INDIM], b[INDIM], acc[INDIM];
#pragma unroll
            for (int j = 0; j < INDIM; ++j) {
                w[j] = ew[j];
                b[j] = eb[j];
                acc[j] = 0.f;
            }
            int beg = row_ptr[node], end = row_ptr[node + 1];
            int2 r;
            if (beg + qt < end) r = csr[beg + qt];
            for (int e = beg + qt; e < end; e += 2) {
                int2 rn = (e + 2 < end) ? csr[e + 2] : r;
                float a = __int_as_float(r.y);
#pragma unroll
                for (int j = 0; j < INDIM; ++j)
                    acc[j] += fmaxf(fmaf(a, w[j], xinf[r.x * INDIM + j] + b[j]), 0.f);
                r = rn;
            }
#pragma unroll
            for (int j = 0; j < INDIM; ++j) u.part[row][qt][j] = acc[j];
        }
        __syncthreads();
        if (tid < NPBLK) {
            int nd = min(node0 + tid, N_NODES - 1);
#pragma unroll
            for (int j = 0; j < INDIM; ++j) {
                float v = xinf[nd * INDIM + j] + u.part[tid][0][j] + u.part[tid][1][j];
                A16[tid * LDA + j] = cvt1_bf(v);
            }
#pragma unroll
            for (int j = INDIM; j < 32; ++j) A16[tid * LDA + j] = 0;
        }
        __syncthreads();  // rows written by tid<128 -> cross-wave
    }

    // ---- MFMA MLP: 32 wave-local rows = 2 row-groups sharing each bh load ----
    int wv = tid >> 6, lane = tid & 63;
    int mrow = lane & 15, q = lane >> 4;
    int ar0 = wv * 32 + mrow;        // group 0 A-row
    int ar1 = wv * 32 + 16 + mrow;   // group 1 A-row

    const short8* w1p = (const short8*)w1h;
    const short8* w2p = (const short8*)w2h;

    f32x4 acc2[2][8];
#pragma unroll
    for (int gg = 0; gg < 2; ++gg)
#pragma unroll
        for (int t = 0; t < 8; ++t) acc2[gg][t] = (f32x4){0.f, 0.f, 0.f, 0.f};
    constexpr int KS1 = KP1 / 32;
#pragma unroll
    for (int ks = 0; ks < KS1; ++ks) {
        short8 bh[8];
#pragma unroll
        for (int t = 0; t < 8; ++t) bh[t] = w1p[((size_t)t * KS1 + ks) * 64 + lane];
        short8 ah0 = *(const short8*)&A16[ar0 * LDA + ks * 32 + q * 8];
        short8 ah1 = *(const short8*)&A16[ar1 * LDA + ks * 32 + q * 8];
#pragma unroll
        for (int t = 0; t < 8; ++t) {
            acc2[0][t] = __builtin_amdgcn_mfma_f32_16x16x32_bf16(ah0, bh[t], acc2[0][t], 0, 0, 0);
            acc2[1][t] = __builtin_amdgcn_mfma_f32_16x16x32_bf16(ah1, bh[t], acc2[1][t], 0, 0, 0);
        }
    }
    // t1 = relu(acc + b1) -> bf16 A (wave-local rows)
    {
        float b1v[8];
#pragma unroll
        for (int t = 0; t < 8; ++t) b1v[t] = b1[t * 16 + mrow];
#pragma unroll
        for (int gg = 0; gg < 2; ++gg)
#pragma unroll
            for (int t = 0; t < 8; ++t)
#pragma unroll
                for (int r = 0; r < 4; ++r) {
                    int rrow = wv * 32 + gg * 16 + q * 4 + r;
                    int col = t * 16 + mrow;
                    A16[rrow * LDA + col] = cvt1_bf(fmaxf(acc2[gg][t][r] + b1v[t], 0.f));
                }
    }

    // GEMM2 (K = 128); wave-local A reads
#pragma unroll
    for (int gg = 0; gg < 2; ++gg)
#pragma unroll
        for (int t = 0; t < 8; ++t) acc2[gg][t] = (f32x4){0.f, 0.f, 0.f, 0.f};
#pragma unroll
    for (int ks = 0; ks < 4; ++ks) {
        short8 bh[8];
#pragma unroll
        for (int t = 0; t < 8; ++t) bh[t] = w2p[((size_t)t * 4 + ks) * 64 + lane];
        short8 ah0 = *(const short8*)&A16[ar0 * LDA + ks * 32 + q * 8];
        short8 ah1 = *(const short8*)&A16[ar1 * LDA + ks * 32 + q * 8];
#pragma unroll
        for (int t = 0; t < 8; ++t) {
            acc2[0][t] = __builtin_amdgcn_mfma_f32_16x16x32_bf16(ah0, bh[t], acc2[0][t], 0, 0, 0);
            acc2[1][t] = __builtin_amdgcn_mfma_f32_16x16x32_bf16(ah1, bh[t], acc2[1][t], 0, 0, 0);
        }
    }

    // ---- LayerNorm in registers (both row-groups) ----
    float s4[2][4], q4[2][4];
#pragma unroll
    for (int gg = 0; gg < 2; ++gg)
#pragma unroll
        for (int r = 0; r < 4; ++r) { s4[gg][r] = 0.f; q4[gg][r] = 0.f; }
    {
        float b2v[8];
#pragma unroll
        for (int t = 0; t < 8; ++t) b2v[t] = b2[t * 16 + mrow];
#pragma unroll
        for (int gg = 0; gg < 2; ++gg)
#pragma unroll
            for (int t = 0; t < 8; ++t)
#pragma unroll
                for (int r = 0; r < 4; ++r) {
                    float v = acc2[gg][t][r] + b2v[t];
                    acc2[gg][t][r] = v;
                    s4[gg][r] += v;
                    q4[gg][r] += v * v;
                }
    }
#pragma unroll
    for (int m = 1; m <= 8; m <<= 1) {
#pragma unroll
        for (int gg = 0; gg < 2; ++gg)
#pragma unroll
            for (int r = 0; r < 4; ++r) {
                s4[gg][r] += __shfl_xor(s4[gg][r], m, 64);
                q4[gg][r] += __shfl_xor(q4[gg][r], m, 64);
            }
    }
    float mu[2][4], inv[2][4];
#pragma unroll
    for (int gg = 0; gg < 2; ++gg)
#pragma unroll
        for (int r = 0; r < 4; ++r) {
            mu[gg][r] = s4[gg][r] * (1.f / HDIM);
            float var = q4[gg][r] * (1.f / HDIM) - mu[gg][r] * mu[gg][r];
            inv[gg][r] = rsqrtf(var + LN_EPS);
        }
    float gv[8], btv[8];
#pragma unroll
    for (int t = 0; t < 8; ++t) {
        gv[t] = g[t * 16 + mrow];
        btv[t] = bt[t * 16 + mrow];
    }

    // LN result -> LDS (wave-local row writes)
#pragma unroll
    for (int gg = 0; gg < 2; ++gg)
#pragma unroll
        for (int t = 0; t < 8; ++t)
#pragma unroll
            for (int r = 0; r < 4; ++r) {
                int rrow = wv * 32 + gg * 16 + q * 4 + r;
                int col = t * 16 + mrow;
                float o = fmaxf((acc2[gg][t][r] - mu[gg][r]) * inv[gg][r] * gv[t] + btv[t], 0.f);
                A16[rrow * LDA + col] = cvt1_bf(o);
            }
    __syncthreads();  // epilogue reads all rows (cross-wave)

    if (!POOL) {
        // coalesced copy-out: 128 rows x 64 dwords = 8192, guarded for the partial last block
        unsigned* xo = (unsigned*)xout;
#pragma unroll
        for (int i = 0; i < 32; ++i) {
            int idx = tid + 256 * i;
            int row = idx >> 6, w = idx & 63;
            if (node0 + row < N_NODES)
                xo[(size_t)(node0 + row) * 64 + w] = ((const unsigned*)&A16[row * LDA])[w];
        }
    } else {
        int rmax = min(NPBLK, N_NODES - node0);
        if (tid < 128) {
            int col = tid;
            float accp = 0.f;
            int cur = bidx[0];
            for (int r = 0; r < rmax; ++r) {
                int gi = bidx[r];
                if (gi != cur) {
                    unsafeAtomicAdd(&pool[cur * HDIM + col], accp);
                    accp = 0.f;
                    cur = gi;
                }
                accp += bf2f(A16[r * LDA + col]);
            }
            unsafeAtomicAdd(&pool[cur * HDIM + col], accp);
        } else if (tid == 255) {
            int cur = bidx[0], c = 0;
            for (int r = 0; r < rmax; ++r) {
                if (bidx[r] != cur) {
                    atomicAdd(&cnt[cur], c);
                    c = 0;
                    cur = bidx[r];
                }
                ++c;
            }
            atomicAdd(&cnt[cur], c);
        }
    }
}

__global__ void pool_final(const float* __restrict__ pool, const int* __restrict__ cnt,
                           float* __restrict__ out) {
    int g = blockIdx.x, j = threadIdx.x;
    float add = pool[g * HDIM + j];
    float c = (float)max(cnt[g], 1);
    out[g * (2 * HDIM) + j] = add / c;
    out[g * (2 * HDIM) + HDIM + j] = add;
}

extern "C" void kernel_launch(void* const* d_in, const int* in_sizes, int n_in,
                              void* d_out, int out_size, void* d_ws, size_t ws_size,
                              hipStream_t stream) {
    const float* x_in = (const float*)d_in[0];
    const int* ei = (const int*)d_in[1];
    const float* ea = (const float*)d_in[2];
    const int* batch = (const int*)d_in[3];
    const float* P[24];
    for (int i = 0; i < 24; ++i) P[i] = (const float*)d_in[4 + i];
    // per layer l (base 8l): 0=ew 1=eb 2=w1 3=b1 4=w2 5=b2 6=g 7=bt

    unsigned short* x_a = (unsigned short*)d_ws;                 // N*128 bf16
    unsigned short* x_b = x_a + (size_t)N_NODES * HDIM;          // N*128 bf16
    float* pool = (float*)(x_b + (size_t)N_NODES * HDIM);        // G*128 (zeroed in scanA)
    int* cnt = (int*)(pool + N_GRAPHS * HDIM);                   // G    (zeroed in scanA)
    int* deg = cnt + N_GRAPHS;                                   // N    (memset)
    int* cursor = deg + N_NODES;                                 // N    (zeroed in scanC)
    int* row_ptr = cursor + N_NODES;                             // N+1
    int* bsums = row_ptr + N_NODES + 1;                          // pad 256 (keeps int2 8B-aligned)
    int2* csr = (int2*)(bsums + 256);                            // E (packed {src, val})
    short* wp = (short*)(((uintptr_t)(csr + N_EDGES) + 15) & ~(uintptr_t)15);
    float* out = (float*)d_out;

    short *w1h[3], *w2h[3];
    for (int l = 0; l < 3; ++l) {
        w1h[l] = wp + (size_t)l * 32768;
        w2h[l] = w1h[l] + 16384;
    }

    // ---- memset: deg only (pool/cnt zeroed in scanA, cursor in scanC) ----
    hipMemsetAsync(deg, 0, N_NODES * sizeof(int), stream);

    // ---- CSR build ----
    hist_kernel<<<(N_EDGES + 255) / 256, 256, 0, stream>>>(ei, deg);
    scan_phaseA<<<SCAN_BLOCKS, 256, 0, stream>>>(deg, bsums, (int*)pool);
    scan_phaseB<<<1, 256, 0, stream>>>(bsums, row_ptr);
    scan_phaseC<<<SCAN_BLOCKS, 256, 0, stream>>>(deg, bsums, row_ptr, cursor);

    // ---- fused scatter + weight packing (1563 + 336 blocks) ----
    scatter_pack<<<SCATTER_BLOCKS + 336, 256, 0, stream>>>(
        ei, ea, row_ptr, cursor, csr,
        P[2], w1h[0], P[4], w2h[0],
        P[10], w1h[1], P[12], w2h[1],
        P[18], w1h[2], P[20], w2h[2]);

    // ---- fused layers ----
    layer_fused<32, false><<<NBLKS, 256, 0, stream>>>(
        x_in, row_ptr, csr, P[0], P[1],
        w1h[0], P[3], w2h[0], P[5], P[6], P[7], x_a, nullptr, nullptr, nullptr);
    layer_fused<128, false><<<NBLKS, 256, 0, stream>>>(
        x_a, row_ptr, csr, P[8], P[9],
        w1h[1], P[11], w2h[1], P[13], P[14], P[15], x_b, nullptr, nullptr, nullptr);
    layer_fused<128, true><<<NBLKS, 256, 0, stream>>>(
        x_b, row_ptr, csr, P[16], P[17],
        w1h[2], P[19], w2h[2], P[21], P[22], P[23], nullptr, batch, pool, cnt);

    pool_final<<<N_GRAPHS, HDIM, 0, stream>>>(pool, cnt, out);
}

// Round 12
// 365.735 us; speedup vs baseline: 1.8276x; 1.8276x over previous
//
#include <hip/hip_runtime.h>

#define N_NODES 200000
#define N_EDGES 400000
#define N_GRAPHS 64
#define HDIM 128
#define INDIM 5
#define LN_EPS 1e-5f
#define LDA 140  // 70 dwords/row: 70 mod 32 = 6 -> frag reads distributed; 2-way-only write aliasing
#define NPBLK 64 // nodes per block (4 waves x 16 wave-local rows -- R0/R8-proven config)

typedef __attribute__((ext_vector_type(8))) short short8;
typedef __attribute__((ext_vector_type(4))) float f32x4;
typedef __attribute__((ext_vector_type(2))) float f32x2;

__device__ __forceinline__ unsigned short to_bf(float v) {
    unsigned u = __builtin_bit_cast(unsigned, v);
    return (unsigned short)((u + 0x7FFFu + ((u >> 16) & 1u)) >> 16);
}
__device__ __forceinline__ float bf_lo(unsigned w) { return __builtin_bit_cast(float, w << 16); }
__device__ __forceinline__ float bf_hi(unsigned w) { return __builtin_bit_cast(float, w & 0xFFFF0000u); }
__device__ __forceinline__ float bf2f(unsigned short h) { return __builtin_bit_cast(float, (unsigned)h << 16); }

// 1-instr RTNE f32->bf16 (same rounding as to_bf)
__device__ __forceinline__ unsigned short cvt1_bf(float v) {
    unsigned r;
    asm("v_cvt_pk_bf16_f32 %0, %1, %1" : "=v"(r) : "v"(v));
    return (unsigned short)r;
}
__device__ __forceinline__ unsigned cvt2_bf(float lo, float hi) {
    unsigned r;
    asm("v_cvt_pk_bf16_f32 %0, %1, %2" : "=v"(r) : "v"(lo), "v"(hi));
    return r;
}
__device__ __forceinline__ f32x2 vmax0(f32x2 v) {
#if __has_builtin(__builtin_elementwise_max)
    return __builtin_elementwise_max(v, (f32x2)0.f);
#else
    v.x = fmaxf(v.x, 0.f);
    v.y = fmaxf(v.y, 0.f);
    return v;
#endif
}

// ---- gather macros: 32 ch/thread (16 dwords = 4 uint4). Literal indices only,
// no staging arrays, no pointer-passed locals (R1/R3 lessons), no token pasting (R2).
#define GLOAD(p0, p1, p2, p3, srcrow)                                       \
    {                                                                       \
        const uint4* xs_ = (const uint4*)(xin + (size_t)(srcrow)*128 + c0); \
        p0 = xs_[0]; p1 = xs_[1]; p2 = xs_[2]; p3 = xs_[3];                 \
    }

// one dword wd = channel pair (2*i0, 2*i0+1): accv += relu((x + eb) + a*ew), packed f32x2
#define GP2(wd, i0)            \
    {                          \
        float4 wb_ = ep[i0];   \
        f32x2 xv_;             \
        xv_.x = bf_lo(wd);     \
        xv_.y = bf_hi(wd);     \
        f32x2 ew_, eb_;        \
        ew_.x = wb_.x;         \
        ew_.y = wb_.y;         \
        eb_.x = wb_.z;         \
        eb_.y = wb_.w;         \
        f32x2 t_ = xv_ + eb_;  \
        t_ = av2_ * ew_ + t_;  \
        accv[i0] += vmax0(t_); \
    }

#define GPROC(p0, p1, p2, p3, a_)                               \
    {                                                           \
        f32x2 av2_;                                             \
        av2_.x = (a_);                                          \
        av2_.y = (a_);                                          \
        GP2(p0.x, 0) GP2(p0.y, 1) GP2(p0.z, 2) GP2(p0.w, 3)     \
        GP2(p1.x, 4) GP2(p1.y, 5) GP2(p1.z, 6) GP2(p1.w, 7)     \
        GP2(p2.x, 8) GP2(p2.y, 9) GP2(p2.z, 10) GP2(p2.w, 11)   \
        GP2(p3.x, 12) GP2(p3.y, 13) GP2(p3.z, 14) GP2(p3.w, 15) \
    }

#define GI2(wd, i0)             \
    {                           \
        accv[i0].x = bf_lo(wd); \
        accv[i0].y = bf_hi(wd); \
    }

#define GINIT(p0, p1, p2, p3)                                   \
    {                                                           \
        GI2(p0.x, 0) GI2(p0.y, 1) GI2(p0.z, 2) GI2(p0.w, 3)     \
        GI2(p1.x, 4) GI2(p1.y, 5) GI2(p1.z, 6) GI2(p1.w, 7)     \
        GI2(p2.x, 8) GI2(p2.y, 9) GI2(p2.z, 10) GI2(p2.w, 11)   \
        GI2(p3.x, 12) GI2(p3.y, 13) GI2(p3.z, 14) GI2(p3.w, 15) \
    }

// ---------------- CSR build ----------------

__global__ void hist_kernel(const int* __restrict__ ei, int* __restrict__ deg) {
    int e = blockIdx.x * blockDim.x + threadIdx.x;
    if (e < N_EDGES) atomicAdd(&deg[ei[N_EDGES + e]], 1);
}

#define SCAN_CHUNK 1024
#define SCAN_BLOCKS ((N_NODES + SCAN_CHUNK - 1) / SCAN_CHUNK)  // 196

__global__ __launch_bounds__(256) void scan_phaseA(const int* __restrict__ deg, int* __restrict__ bsums,
                                                   int* __restrict__ poolz) {
    if (blockIdx.x == 0) {
        for (int i = threadIdx.x; i < N_GRAPHS * HDIM + N_GRAPHS; i += 256) poolz[i] = 0;
    }
    __shared__ int red[256];
    int t = threadIdx.x;
    int base = blockIdx.x * SCAN_CHUNK + t * 4;
    int s = 0;
#pragma unroll
    for (int k = 0; k < 4; ++k) {
        int i = base + k;
        s += (i < N_NODES) ? deg[i] : 0;
    }
    red[t] = s;
    __syncthreads();
    for (int off = 128; off; off >>= 1) {
        if (t < off) red[t] += red[t + off];
        __syncthreads();
    }
    if (t == 0) bsums[blockIdx.x] = red[0];
}

__global__ __launch_bounds__(256) void scan_phaseB(int* __restrict__ bsums, int* __restrict__ row_ptr) {
    __shared__ int s[256];
    int t = threadIdx.x;
    int v = (t < SCAN_BLOCKS) ? bsums[t] : 0;
    s[t] = v;
    __syncthreads();
    for (int off = 1; off < 256; off <<= 1) {
        int add = (t >= off) ? s[t - off] : 0;
        __syncthreads();
        s[t] += add;
        __syncthreads();
    }
    if (t < SCAN_BLOCKS) bsums[t] = s[t] - v;  // exclusive
    if (t == SCAN_BLOCKS - 1) row_ptr[N_NODES] = s[t];
}

__global__ __launch_bounds__(256) void scan_phaseC(const int* __restrict__ deg,
                                                   const int* __restrict__ bsums,
                                                   int* __restrict__ row_ptr,
                                                   int* __restrict__ cursor) {
    __shared__ int ts[256];
    int t = threadIdx.x;
    int base = blockIdx.x * SCAN_CHUNK + t * 4;
    int v[4];
    int s = 0;
#pragma unroll
    for (int k = 0; k < 4; ++k) {
        int i = base + k;
        v[k] = (i < N_NODES) ? deg[i] : 0;
        s += v[k];
    }
    ts[t] = s;
    __syncthreads();
    for (int off = 1; off < 256; off <<= 1) {
        int add = (t >= off) ? ts[t - off] : 0;
        __syncthreads();
        ts[t] += add;
        __syncthreads();
    }
    int run = bsums[blockIdx.x] + ts[t] - s;
#pragma unroll
    for (int k = 0; k < 4; ++k) {
        int i = base + k;
        if (i < N_NODES) { row_ptr[i] = run; cursor[i] = 0; }
        run += v[k];
    }
}

// ---------------- Fused scatter (CSR fill) + weight packing ----------------
#define SCATTER_BLOCKS ((N_EDGES + 255) / 256)  // 1563

__global__ void scatter_pack(const int* __restrict__ ei, const float* __restrict__ ea,
                             const int* __restrict__ row_ptr, int* __restrict__ cursor,
                             int2* __restrict__ csr,
                             const float* __restrict__ s0, short* __restrict__ d0,
                             const float* __restrict__ s1, short* __restrict__ d1,
                             const float* __restrict__ s2, short* __restrict__ d2,
                             const float* __restrict__ s3, short* __restrict__ d3,
                             const float* __restrict__ s4, short* __restrict__ d4,
                             const float* __restrict__ s5, short* __restrict__ d5) {
    int b = blockIdx.x;
    if (b < SCATTER_BLOCKS) {
        int e = b * 256 + threadIdx.x;
        if (e >= N_EDGES) return;
        int d = ei[N_EDGES + e];
        int pos = atomicAdd(&cursor[d], 1);
        csr[row_ptr[d] + pos] = make_int2(ei[e], __float_as_int(ea[e]));
        return;
    }
    b -= SCATTER_BLOCKS;
    const float* W;
    short* D;
    int din, KP, b0;
    if (b < 16)       { W = s0; D = d0; din = 5;   KP = 32;  b0 = 0; }
    else if (b < 80)  { W = s1; D = d1; din = 128; KP = 128; b0 = 16; }
    else if (b < 144) { W = s2; D = d2; din = 128; KP = 128; b0 = 80; }
    else if (b < 208) { W = s3; D = d3; din = 128; KP = 128; b0 = 144; }
    else if (b < 272) { W = s4; D = d4; din = 128; KP = 128; b0 = 208; }
    else              { W = s5; D = d5; din = 128; KP = 128; b0 = 272; }
    int idx = (b - b0) * 256 + threadIdx.x;
    if (idx >= KP * 128) return;
    int j = idx & 7;
    int lane = (idx >> 3) & 63;
    int rest = idx >> 9;
    int KS = KP >> 5;
    int kstep = rest % KS;
    int tile = rest / KS;
    int k = kstep * 32 + ((lane >> 4) * 8) + j;
    int n = tile * 16 + (lane & 15);
    float v = (k < din) ? W[k * 128 + n] : 0.f;
    D[idx] = (short)to_bf(v);
}

// ---------------- Fused layer: gather + MFMA MLP + reg-LN + ReLU (+pool) ----------------
// R8 base (verified 90us/layer, clean counters, 64-VGPR live set) + w1 staged in LDS.
// Staging completes before the EXISTING pre-gather barrier -> tail reads it wave-locally
// with NO new barrier (no R5-style convoy). LDS ~52KB -> 3 blocks/CU, >= the measured
// effective occupancy (2.65 blocks), so no concurrency loss. GEMM2's w2 (32KB) then
// owns L1. 64-VGPR straitjacket respected (R3/R4/R10: allocator never grants more).
template <int KP1, bool POOL>
__global__ __launch_bounds__(256, 4) void layer_fused(
    const void* __restrict__ xin_v, const int* __restrict__ row_ptr,
    const int2* __restrict__ csr,
    const float* __restrict__ ew, const float* __restrict__ eb,
    const short* __restrict__ w1h, const float* __restrict__ b1,
    const short* __restrict__ w2h, const float* __restrict__ b2,
    const float* __restrict__ g, const float* __restrict__ bt,
    unsigned short* __restrict__ xout,
    const int* __restrict__ batch, float* __restrict__ pool, int* __restrict__ cnt) {
    __shared__ __align__(16) unsigned short A16[NPBLK * LDA];
    __shared__ __align__(16) short w1s[KP1 * 128];  // 32KB (KP1=128) / 8KB (KP1=32)
    __shared__ int bidx[NPBLK];
    union Scratch {
        float4 eweb4[4 * 17];                          // {ew,ew,eb,eb} pairs, qt-stride 17 (conflict-free)
        float part[KP1 == 128 ? 1 : NPBLK][4][INDIM];  // layer-0 gather partials
    };
    __shared__ __align__(16) Scratch u;

    int tid = threadIdx.x;
    int node0 = blockIdx.x * NPBLK;

    // ---- stage w1 -> LDS (coalesced; completes before the pre-gather barrier) ----
    {
        short8* d8 = (short8*)w1s;
        const short8* s8 = (const short8*)w1h;
#pragma unroll
        for (int i = 0; i < (KP1 * 128 / 8) / 256; ++i) d8[i * 256 + tid] = s8[i * 256 + tid];
    }

    if constexpr (KP1 == 128) {
        const unsigned short* xin = (const unsigned short*)xin_v;
        // stage padded edge-encoder table (conflict-free broadcast reads: qt groups 4 banks apart)
        if (tid < 64) {
            int qq = tid >> 4, ii = tid & 15, c = qq * 32 + ii * 2;
            u.eweb4[qq * 17 + ii] = make_float4(ew[c], ew[c + 1], eb[c], eb[c + 1]);
        }
        if (POOL && tid >= 64 && tid < 128) bidx[tid - 64] = batch[node0 + tid - 64];

        // thread = (row, 32-channel quarter)
        int row = tid >> 2, qt = tid & 3, c0 = qt * 32;
        int node = node0 + row;

        // own-row + pipeline prologue issued before the barrier (in flight across it)
        const uint4* xn = (const uint4*)(xin + (size_t)node * 128 + c0);
        uint4 o0 = xn[0], o1 = xn[1], o2 = xn[2], o3 = xn[3];
        int beg = row_ptr[node], end = row_ptr[node + 1];

        uint4 va0, va1, va2, va3;
        float aA = 0.f;
        int2 rC = make_int2(0, 0), rD = rC;
        if (beg < end) {
            int2 r = csr[beg];
            aA = __int_as_float(r.y);
            GLOAD(va0, va1, va2, va3, r.x);
        }
        if (beg + 1 < end) rC = csr[beg + 1];
        if (beg + 2 < end) rD = csr[beg + 2];
        __syncthreads();  // eweb4 + w1s ready
        const float4* ep = u.eweb4 + qt * 17;

        f32x2 accv[16];
        GINIT(o0, o1, o2, o3);

        // 1-deep x pipeline + distance-2 csr prefetch (R6-proven codegen):
        // record for edge e+1 is RESIDENT when its GLOAD issues; csr never on the chain.
        int e = beg;
        while (e + 1 < end) {
            GPROC(va0, va1, va2, va3, aA);   // waits on this edge's x only
            aA = __int_as_float(rC.y);
            GLOAD(va0, va1, va2, va3, rC.x); // rC resident -> issue immediately
            rC = rD;                         // rD in flight since last iter (cheap partial wait)
            int i3 = min(e + 3, end - 1);    // unconditional clamped (no branch-merge waitcnt)
            rD = csr[i3];
            ++e;
        }
        if (e < end) GPROC(va0, va1, va2, va3, aA);

        // packed cvt + uint2 stores (2-way bank aliasing only = free)
        uint2* Ar2 = (uint2*)&A16[row * LDA + c0];
#pragma unroll
        for (int k = 0; k < 8; ++k) {
            Ar2[k] = make_uint2(cvt2_bf(accv[2 * k].x, accv[2 * k].y),
                                cvt2_bf(accv[2 * k + 1].x, accv[2 * k + 1].y));
        }
        // no barrier: rows [16wv,16wv+16) are written and read by the same wave
    } else {
        // layer 0 (din=5): 4 threads/row split the edge list; register partials
        const float* xinf = (const float*)xin_v;
        int row = tid >> 2, qt = tid & 3;
        int node = node0 + row;
        {
            float w[INDIM], b[INDIM], acc[INDIM];
#pragma unroll
            for (int j = 0; j < INDIM; ++j) {
                w[j] = ew[j];
                b[j] = eb[j];
                acc[j] = 0.f;
            }
            int beg = row_ptr[node], end = row_ptr[node + 1];
            int2 r;
            if (beg + qt < end) r = csr[beg + qt];
            for (int e = beg + qt; e < end; e += 4) {
                int2 rn = (e + 4 < end) ? csr[e + 4] : r;
                float a = __int_as_float(r.y);
#pragma unroll
                for (int j = 0; j < INDIM; ++j)
                    acc[j] += fmaxf(fmaf(a, w[j], xinf[r.x * INDIM + j] + b[j]), 0.f);
                r = rn;
            }
#pragma unroll
            for (int j = 0; j < INDIM; ++j) u.part[row][qt][j] = acc[j];
        }
        __syncthreads();  // part + w1s ready
        if (tid < NPBLK) {
#pragma unroll
            for (int j = 0; j < INDIM; ++j) {
                float v = xinf[(node0 + tid) * INDIM + j] + u.part[tid][0][j] + u.part[tid][1][j] +
                          u.part[tid][2][j] + u.part[tid][3][j];
                A16[tid * LDA + j] = cvt1_bf(v);
            }
#pragma unroll
            for (int j = INDIM; j < 32; ++j) A16[tid * LDA + j] = 0;
        }
        __syncthreads();  // rows written by tid<64 -> cross-wave
    }

    // ---- MFMA MLP (wave-local rows); w1 from LDS, w2 from global (L1-resident) ----
    int wv = tid >> 6, lane = tid & 63;
    int mrow = lane & 15, q = lane >> 4;
    int arow = wv * 16 + mrow;

    const short8* w1p = (const short8*)w1s;
    const short8* w2p = (const short8*)w2h;

    f32x4 acc2[8];
#pragma unroll
    for (int t = 0; t < 8; ++t) acc2[t] = (f32x4){0.f, 0.f, 0.f, 0.f};
    constexpr int KS1 = KP1 / 32;
#pragma unroll
    for (int ks = 0; ks < KS1; ++ks) {
        short8 bh[8];
#pragma unroll
        for (int t = 0; t < 8; ++t) bh[t] = w1p[((size_t)t * KS1 + ks) * 64 + lane];
        short8 ah = *(const short8*)&A16[arow * LDA + ks * 32 + q * 8];
#pragma unroll
        for (int t = 0; t < 8; ++t)
            acc2[t] = __builtin_amdgcn_mfma_f32_16x16x32_bf16(ah, bh[t], acc2[t], 0, 0, 0);
    }
    // t1 = relu(acc + b1) -> bf16 A (wave-local rows)
    {
        float b1v[8];
#pragma unroll
        for (int t = 0; t < 8; ++t) b1v[t] = b1[t * 16 + mrow];
#pragma unroll
        for (int t = 0; t < 8; ++t)
#pragma unroll
            for (int r = 0; r < 4; ++r) {
                int rrow = wv * 16 + q * 4 + r;
                int col = t * 16 + mrow;
                A16[rrow * LDA + col] = cvt1_bf(fmaxf(acc2[t][r] + b1v[t], 0.f));
            }
    }

    // GEMM2 (K = 128); A reads wave-local
#pragma unroll
    for (int t = 0; t < 8; ++t) acc2[t] = (f32x4){0.f, 0.f, 0.f, 0.f};
#pragma unroll
    for (int ks = 0; ks < 4; ++ks) {
        short8 bh[8];
#pragma unroll
        for (int t = 0; t < 8; ++t) bh[t] = w2p[((size_t)t * 4 + ks) * 64 + lane];
        short8 ah = *(const short8*)&A16[arow * LDA + ks * 32 + q * 8];
#pragma unroll
        for (int t = 0; t < 8; ++t)
            acc2[t] = __builtin_amdgcn_mfma_f32_16x16x32_bf16(ah, bh[t], acc2[t], 0, 0, 0);
    }

    // ---- LayerNorm in registers (rows live in 16-lane groups) ----
    float s4[4] = {0.f, 0.f, 0.f, 0.f}, q4[4] = {0.f, 0.f, 0.f, 0.f};
    {
        float b2v[8];
#pragma unroll
        for (int t = 0; t < 8; ++t) b2v[t] = b2[t * 16 + mrow];
#pragma unroll
        for (int t = 0; t < 8; ++t)
#pragma unroll
            for (int r = 0; r < 4; ++r) {
                float v = acc2[t][r] + b2v[t];
                acc2[t][r] = v;
                s4[r] += v;
                q4[r] += v * v;
            }
    }
#pragma unroll
    for (int m = 1; m <= 8; m <<= 1) {
#pragma unroll
        for (int r = 0; r < 4; ++r) {
            s4[r] += __shfl_xor(s4[r], m, 64);
            q4[r] += __shfl_xor(q4[r], m, 64);
        }
    }
    float mu[4], inv[4];
#pragma unroll
    for (int r = 0; r < 4; ++r) {
        mu[r] = s4[r] * (1.f / HDIM);
        float var = q4[r] * (1.f / HDIM) - mu[r] * mu[r];
        inv[r] = rsqrtf(var + LN_EPS);
    }
    float gv[8], btv[8];
#pragma unroll
    for (int t = 0; t < 8; ++t) {
        gv[t] = g[t * 16 + mrow];
        btv[t] = bt[t * 16 + mrow];
    }

    // LN result -> LDS (wave-local row writes; no pre-barrier needed)
#pragma unroll
    for (int t = 0; t < 8; ++t)
#pragma unroll
        for (int r = 0; r < 4; ++r) {
            int rrow = wv * 16 + q * 4 + r;
            int col = t * 16 + mrow;
            float o = fmaxf((acc2[t][r] - mu[r]) * inv[r] * gv[t] + btv[t], 0.f);
            A16[rrow * LDA + col] = cvt1_bf(o);
        }
    __syncthreads();  // epilogue reads all rows (cross-wave)

    if (!POOL) {
        // coalesced copy-out: wave inst covers 256 contiguous bytes (4 full lines)
        unsigned* xo = (unsigned*)xout;
#pragma unroll
        for (int i = 0; i < 16; ++i) {
            int idx = tid + 256 * i;       // 4096 = 64 rows x 64 words
            int row = idx >> 6, w = idx & 63;
            xo[(size_t)(node0 + row) * 64 + w] = ((const unsigned*)&A16[row * LDA])[w];
        }
    } else {
        if (tid < 128) {
            int col = tid;
            float accp = 0.f;
            int cur = bidx[0];
            for (int r = 0; r < NPBLK; ++r) {
                int gi = bidx[r];
                if (gi != cur) {
                    unsafeAtomicAdd(&pool[cur * HDIM + col], accp);
                    accp = 0.f;
                    cur = gi;
                }
                accp += bf2f(A16[r * LDA + col]);
            }
            unsafeAtomicAdd(&pool[cur * HDIM + col], accp);
        } else if (tid == 255) {
            int cur = bidx[0], c = 0;
            for (int r = 0; r < NPBLK; ++r) {
                if (bidx[r] != cur) {
                    atomicAdd(&cnt[cur], c);
                    c = 0;
                    cur = bidx[r];
                }
                ++c;
            }
            atomicAdd(&cnt[cur], c);
        }
    }
}

__global__ void pool_final(const float* __restrict__ pool, const int* __restrict__ cnt,
                           float* __restrict__ out) {
    int g = blockIdx.x, j = threadIdx.x;
    float add = pool[g * HDIM + j];
    float c = (float)max(cnt[g], 1);
    out[g * (2 * HDIM) + j] = add / c;
    out[g * (2 * HDIM) + HDIM + j] = add;
}

extern "C" void kernel_launch(void* const* d_in, const int* in_sizes, int n_in,
                              void* d_out, int out_size, void* d_ws, size_t ws_size,
                              hipStream_t stream) {
    const float* x_in = (const float*)d_in[0];
    const int* ei = (const int*)d_in[1];
    const float* ea = (const float*)d_in[2];
    const int* batch = (const int*)d_in[3];
    const float* P[24];
    for (int i = 0; i < 24; ++i) P[i] = (const float*)d_in[4 + i];
    // per layer l (base 8l): 0=ew 1=eb 2=w1 3=b1 4=w2 5=b2 6=g 7=bt

    unsigned short* x_a = (unsigned short*)d_ws;                 // N*128 bf16
    unsigned short* x_b = x_a + (size_t)N_NODES * HDIM;          // N*128 bf16
    float* pool = (float*)(x_b + (size_t)N_NODES * HDIM);        // G*128 (zeroed in scanA)
    int* cnt = (int*)(pool + N_GRAPHS * HDIM);                   // G    (zeroed in scanA)
    int* deg = cnt + N_GRAPHS;                                   // N    (memset)
    int* cursor = deg + N_NODES;                                 // N    (zeroed in scanC)
    int* row_ptr = cursor + N_NODES;                             // N+1
    int* bsums = row_ptr + N_NODES + 1;                          // pad 256 (keeps int2 8B-aligned)
    int2* csr = (int2*)(bsums + 256);                            // E (packed {src, val})
    short* wp = (short*)(((uintptr_t)(csr + N_EDGES) + 15) & ~(uintptr_t)15);
    float* out = (float*)d_out;

    short *w1h[3], *w2h[3];
    for (int l = 0; l < 3; ++l) {
        w1h[l] = wp + (size_t)l * 32768;
        w2h[l] = w1h[l] + 16384;
    }

    // ---- memset: deg only (pool/cnt zeroed in scanA, cursor in scanC) ----
    hipMemsetAsync(deg, 0, N_NODES * sizeof(int), stream);

    // ---- CSR build ----
    hist_kernel<<<(N_EDGES + 255) / 256, 256, 0, stream>>>(ei, deg);
    scan_phaseA<<<SCAN_BLOCKS, 256, 0, stream>>>(deg, bsums, (int*)pool);
    scan_phaseB<<<1, 256, 0, stream>>>(bsums, row_ptr);
    scan_phaseC<<<SCAN_BLOCKS, 256, 0, stream>>>(deg, bsums, row_ptr, cursor);

    // ---- fused scatter + weight packing (1563 + 336 blocks) ----
    scatter_pack<<<SCATTER_BLOCKS + 336, 256, 0, stream>>>(
        ei, ea, row_ptr, cursor, csr,
        P[2], w1h[0], P[4], w2h[0],
        P[10], w1h[1], P[12], w2h[1],
        P[18], w1h[2], P[20], w2h[2]);

    // ---- fused layers ----
    layer_fused<32, false><<<N_NODES / NPBLK, 256, 0, stream>>>(
        x_in, row_ptr, csr, P[0], P[1],
        w1h[0], P[3], w2h[0], P[5], P[6], P[7], x_a, nullptr, nullptr, nullptr);
    layer_fused<128, false><<<N_NODES / NPBLK, 256, 0, stream>>>(
        x_a, row_ptr, csr, P[8], P[9],
        w1h[1], P[11], w2h[1], P[13], P[14], P[15], x_b, nullptr, nullptr, nullptr);
    layer_fused<128, true><<<N_NODES / NPBLK, 256, 0, stream>>>(
        x_b, row_ptr, csr, P[16], P[17],
        w1h[2], P[19], w2h[2], P[21], P[22], P[23], nullptr, batch, pool, cnt);

    pool_final<<<N_GRAPHS, HDIM, 0, stream>>>(pool, cnt, out);
}

// Round 13
// 343.752 us; speedup vs baseline: 1.9445x; 1.0639x over previous
//
#include <hip/hip_runtime.h>

#define N_NODES 200000
#define N_EDGES 400000
#define N_GRAPHS 64
#define HDIM 128
#define INDIM 5
#define LN_EPS 1e-5f
#define LDA 140  // 70 dwords/row: 70 mod 32 = 6 -> frag reads distributed; 2-way-only write aliasing
#define NPBLK 64 // nodes per block (4 waves x 16 wave-local rows -- R0/R8-proven config)

typedef __attribute__((ext_vector_type(8))) short short8;
typedef __attribute__((ext_vector_type(4))) float f32x4;
typedef __attribute__((ext_vector_type(2))) float f32x2;

__device__ __forceinline__ unsigned short to_bf(float v) {
    unsigned u = __builtin_bit_cast(unsigned, v);
    return (unsigned short)((u + 0x7FFFu + ((u >> 16) & 1u)) >> 16);
}
__device__ __forceinline__ float bf_lo(unsigned w) { return __builtin_bit_cast(float, w << 16); }
__device__ __forceinline__ float bf_hi(unsigned w) { return __builtin_bit_cast(float, w & 0xFFFF0000u); }
__device__ __forceinline__ float bf2f(unsigned short h) { return __builtin_bit_cast(float, (unsigned)h << 16); }

// 1-instr RTNE f32->bf16 (same rounding as to_bf)
__device__ __forceinline__ unsigned short cvt1_bf(float v) {
    unsigned r;
    asm("v_cvt_pk_bf16_f32 %0, %1, %1" : "=v"(r) : "v"(v));
    return (unsigned short)r;
}
__device__ __forceinline__ unsigned cvt2_bf(float lo, float hi) {
    unsigned r;
    asm("v_cvt_pk_bf16_f32 %0, %1, %2" : "=v"(r) : "v"(lo), "v"(hi));
    return r;
}
__device__ __forceinline__ f32x2 vmax0(f32x2 v) {
#if __has_builtin(__builtin_elementwise_max)
    return __builtin_elementwise_max(v, (f32x2)0.f);
#else
    v.x = fmaxf(v.x, 0.f);
    v.y = fmaxf(v.y, 0.f);
    return v;
#endif
}

// ---- gather macros: 32 ch/thread (16 dwords = 4 uint4). Literal indices only,
// no staging arrays, no pointer-passed locals (R1/R3 lessons), no token pasting (R2).
#define GLOAD(p0, p1, p2, p3, srcrow)                                       \
    {                                                                       \
        const uint4* xs_ = (const uint4*)(xin + (size_t)(srcrow)*128 + c0); \
        p0 = xs_[0]; p1 = xs_[1]; p2 = xs_[2]; p3 = xs_[3];                 \
    }

// one dword wd = channel pair (2*i0, 2*i0+1): accv += relu((x + eb) + a*ew), packed f32x2
#define GP2(wd, i0)            \
    {                          \
        float4 wb_ = ep[i0];   \
        f32x2 xv_;             \
        xv_.x = bf_lo(wd);     \
        xv_.y = bf_hi(wd);     \
        f32x2 ew_, eb_;        \
        ew_.x = wb_.x;         \
        ew_.y = wb_.y;         \
        eb_.x = wb_.z;         \
        eb_.y = wb_.w;         \
        f32x2 t_ = xv_ + eb_;  \
        t_ = av2_ * ew_ + t_;  \
        accv[i0] += vmax0(t_); \
    }

#define GPROC(p0, p1, p2, p3, a_)                               \
    {                                                           \
        f32x2 av2_;                                             \
        av2_.x = (a_);                                          \
        av2_.y = (a_);                                          \
        GP2(p0.x, 0) GP2(p0.y, 1) GP2(p0.z, 2) GP2(p0.w, 3)     \
        GP2(p1.x, 4) GP2(p1.y, 5) GP2(p1.z, 6) GP2(p1.w, 7)     \
        GP2(p2.x, 8) GP2(p2.y, 9) GP2(p2.z, 10) GP2(p2.w, 11)   \
        GP2(p3.x, 12) GP2(p3.y, 13) GP2(p3.z, 14) GP2(p3.w, 15) \
    }

#define GI2(wd, i0)             \
    {                           \
        accv[i0].x = bf_lo(wd); \
        accv[i0].y = bf_hi(wd); \
    }

#define GINIT(p0, p1, p2, p3)                                   \
    {                                                           \
        GI2(p0.x, 0) GI2(p0.y, 1) GI2(p0.z, 2) GI2(p0.w, 3)     \
        GI2(p1.x, 4) GI2(p1.y, 5) GI2(p1.z, 6) GI2(p1.w, 7)     \
        GI2(p2.x, 8) GI2(p2.y, 9) GI2(p2.z, 10) GI2(p2.w, 11)   \
        GI2(p3.x, 12) GI2(p3.y, 13) GI2(p3.z, 14) GI2(p3.w, 15) \
    }

// ---------------- CSR build ----------------

__global__ void hist_kernel(const int* __restrict__ ei, int* __restrict__ deg) {
    int e = blockIdx.x * blockDim.x + threadIdx.x;
    if (e < N_EDGES) atomicAdd(&deg[ei[N_EDGES + e]], 1);
}

// graph segment starts via binary search (batch is sorted); gbnd[G] = N automatically
__global__ void gbounds(const int* __restrict__ batch, int* __restrict__ gbnd) {
    int g = threadIdx.x;
    if (g > N_GRAPHS) return;
    int lo = 0, hi = N_NODES;
    while (lo < hi) {
        int mid = (lo + hi) >> 1;
        if (batch[mid] < g) lo = mid + 1;
        else hi = mid;
    }
    gbnd[g] = lo;
}

// per-graph counting sort by degree -> perm (new->orig), iperm (orig->new).
// Within-graph sort keeps batchp globally sorted (pool path unchanged) and
// per-graph pooling is permutation-invariant.
__global__ __launch_bounds__(256) void gsort(const int* __restrict__ deg,
                                             const int* __restrict__ gbnd,
                                             int* __restrict__ perm, int* __restrict__ iperm) {
    __shared__ int bins[64], offs[64];
    int g = blockIdx.x;
    int s = gbnd[g], e2 = gbnd[g + 1];
    int t = threadIdx.x;
    if (t < 64) bins[t] = 0;
    __syncthreads();
    for (int i = s + t; i < e2; i += 256) atomicAdd(&bins[min(deg[i], 63)], 1);
    __syncthreads();
    if (t == 0) {
        int run = 0;
        for (int b = 0; b < 64; ++b) { offs[b] = run; run += bins[b]; }
    }
    __syncthreads();
    if (t < 64) bins[t] = 0;  // reuse as running rank counters
    __syncthreads();
    for (int i = s + t; i < e2; i += 256) {
        int b = min(deg[i], 63);
        int r = atomicAdd(&bins[b], 1);
        int pos = s + offs[b] + r;
        perm[pos] = i;
        iperm[i] = pos;
    }
}

__global__ void permute_kernel(const int* __restrict__ perm, const int* __restrict__ deg,
                               const int* __restrict__ batch, const float* __restrict__ x_in,
                               int* __restrict__ degp, int* __restrict__ batchp,
                               float* __restrict__ xp) {
    int p = blockIdx.x * 256 + threadIdx.x;
    if (p >= N_NODES) return;
    int o = perm[p];
    degp[p] = deg[o];
    batchp[p] = batch[o];
#pragma unroll
    for (int j = 0; j < INDIM; ++j) xp[p * INDIM + j] = x_in[o * INDIM + j];
}

#define SCAN_CHUNK 1024
#define SCAN_BLOCKS ((N_NODES + SCAN_CHUNK - 1) / SCAN_CHUNK)  // 196

__global__ __launch_bounds__(256) void scan_phaseA(const int* __restrict__ deg, int* __restrict__ bsums,
                                                   int* __restrict__ poolz) {
    if (blockIdx.x == 0) {
        for (int i = threadIdx.x; i < N_GRAPHS * HDIM + N_GRAPHS; i += 256) poolz[i] = 0;
    }
    __shared__ int red[256];
    int t = threadIdx.x;
    int base = blockIdx.x * SCAN_CHUNK + t * 4;
    int s = 0;
#pragma unroll
    for (int k = 0; k < 4; ++k) {
        int i = base + k;
        s += (i < N_NODES) ? deg[i] : 0;
    }
    red[t] = s;
    __syncthreads();
    for (int off = 128; off; off >>= 1) {
        if (t < off) red[t] += red[t + off];
        __syncthreads();
    }
    if (t == 0) bsums[blockIdx.x] = red[0];
}

__global__ __launch_bounds__(256) void scan_phaseB(int* __restrict__ bsums, int* __restrict__ row_ptr) {
    __shared__ int s[256];
    int t = threadIdx.x;
    int v = (t < SCAN_BLOCKS) ? bsums[t] : 0;
    s[t] = v;
    __syncthreads();
    for (int off = 1; off < 256; off <<= 1) {
        int add = (t >= off) ? s[t - off] : 0;
        __syncthreads();
        s[t] += add;
        __syncthreads();
    }
    if (t < SCAN_BLOCKS) bsums[t] = s[t] - v;  // exclusive
    if (t == SCAN_BLOCKS - 1) row_ptr[N_NODES] = s[t];
}

__global__ __launch_bounds__(256) void scan_phaseC(const int* __restrict__ deg,
                                                   const int* __restrict__ bsums,
                                                   int* __restrict__ row_ptr,
                                                   int* __restrict__ cursor) {
    __shared__ int ts[256];
    int t = threadIdx.x;
    int base = blockIdx.x * SCAN_CHUNK + t * 4;
    int v[4];
    int s = 0;
#pragma unroll
    for (int k = 0; k < 4; ++k) {
        int i = base + k;
        v[k] = (i < N_NODES) ? deg[i] : 0;
        s += v[k];
    }
    ts[t] = s;
    __syncthreads();
    for (int off = 1; off < 256; off <<= 1) {
        int add = (t >= off) ? ts[t - off] : 0;
        __syncthreads();
        ts[t] += add;
        __syncthreads();
    }
    int run = bsums[blockIdx.x] + ts[t] - s;
#pragma unroll
    for (int k = 0; k < 4; ++k) {
        int i = base + k;
        if (i < N_NODES) { row_ptr[i] = run; cursor[i] = 0; }
        run += v[k];
    }
}

// ---------------- Fused scatter (CSR fill, permuted) + weight packing ----------------
#define SCATTER_BLOCKS ((N_EDGES + 255) / 256)  // 1563

__global__ void scatter_pack(const int* __restrict__ ei, const float* __restrict__ ea,
                             const int* __restrict__ row_ptr, int* __restrict__ cursor,
                             int2* __restrict__ csr, const int* __restrict__ iperm,
                             const float* __restrict__ s0, short* __restrict__ d0,
                             const float* __restrict__ s1, short* __restrict__ d1,
                             const float* __restrict__ s2, short* __restrict__ d2,
                             const float* __restrict__ s3, short* __restrict__ d3,
                             const float* __restrict__ s4, short* __restrict__ d4,
                             const float* __restrict__ s5, short* __restrict__ d5) {
    int b = blockIdx.x;
    if (b < SCATTER_BLOCKS) {
        int e = b * 256 + threadIdx.x;
        if (e >= N_EDGES) return;
        int d = iperm[ei[N_EDGES + e]];
        int src = iperm[ei[e]];
        int pos = atomicAdd(&cursor[d], 1);
        csr[row_ptr[d] + pos] = make_int2(src, __float_as_int(ea[e]));
        return;
    }
    b -= SCATTER_BLOCKS;
    const float* W;
    short* D;
    int din, KP, b0;
    if (b < 16)       { W = s0; D = d0; din = 5;   KP = 32;  b0 = 0; }
    else if (b < 80)  { W = s1; D = d1; din = 128; KP = 128; b0 = 16; }
    else if (b < 144) { W = s2; D = d2; din = 128; KP = 128; b0 = 80; }
    else if (b < 208) { W = s3; D = d3; din = 128; KP = 128; b0 = 144; }
    else if (b < 272) { W = s4; D = d4; din = 128; KP = 128; b0 = 208; }
    else              { W = s5; D = d5; din = 128; KP = 128; b0 = 272; }
    int idx = (b - b0) * 256 + threadIdx.x;
    if (idx >= KP * 128) return;
    int j = idx & 7;
    int lane = (idx >> 3) & 63;
    int rest = idx >> 9;
    int KS = KP >> 5;
    int kstep = rest % KS;
    int tile = rest / KS;
    int k = kstep * 32 + ((lane >> 4) * 8) + j;
    int n = tile * 16 + (lane & 15);
    float v = (k < din) ? W[k * 128 + n] : 0.f;
    D[idx] = (short)to_bf(v);
}

// ---------------- Fused layer: gather + MFMA MLP + reg-LN + ReLU (+pool) ----------------
// R8-verified structure (90us/layer): 256 thr = 4 waves, 64 nodes/block, wave-local tail.
// Node space is degree-sorted (within graph) -> waves see uniform degree, divergence
// ratio ~2.75x -> ~1.1x. Kernel itself is permutation-agnostic and byte-identical to R8.
template <int KP1, bool POOL>
__global__ __launch_bounds__(256, 4) void layer_fused(
    const void* __restrict__ xin_v, const int* __restrict__ row_ptr,
    const int2* __restrict__ csr,
    const float* __restrict__ ew, const float* __restrict__ eb,
    const short* __restrict__ w1h, const float* __restrict__ b1,
    const short* __restrict__ w2h, const float* __restrict__ b2,
    const float* __restrict__ g, const float* __restrict__ bt,
    unsigned short* __restrict__ xout,
    const int* __restrict__ batch, float* __restrict__ pool, int* __restrict__ cnt) {
    __shared__ __align__(16) unsigned short A16[NPBLK * LDA];
    __shared__ int bidx[NPBLK];
    union Scratch {
        float4 eweb4[4 * 17];                          // {ew,ew,eb,eb} pairs, qt-stride 17 (conflict-free)
        float part[KP1 == 128 ? 1 : NPBLK][4][INDIM];  // layer-0 gather partials
    };
    __shared__ __align__(16) Scratch u;

    int tid = threadIdx.x;
    int node0 = blockIdx.x * NPBLK;

    if constexpr (KP1 == 128) {
        const unsigned short* xin = (const unsigned short*)xin_v;
        // stage padded edge-encoder table (conflict-free broadcast reads: qt groups 4 banks apart)
        if (tid < 64) {
            int qq = tid >> 4, ii = tid & 15, c = qq * 32 + ii * 2;
            u.eweb4[qq * 17 + ii] = make_float4(ew[c], ew[c + 1], eb[c], eb[c + 1]);
        }
        if (POOL && tid >= 64 && tid < 128) bidx[tid - 64] = batch[node0 + tid - 64];

        // thread = (row, 32-channel quarter)
        int row = tid >> 2, qt = tid & 3, c0 = qt * 32;
        int node = node0 + row;

        // own-row + pipeline prologue issued before the barrier (in flight across it)
        const uint4* xn = (const uint4*)(xin + (size_t)node * 128 + c0);
        uint4 o0 = xn[0], o1 = xn[1], o2 = xn[2], o3 = xn[3];
        int beg = row_ptr[node], end = row_ptr[node + 1];

        uint4 va0, va1, va2, va3;
        float aA = 0.f;
        int2 rC = make_int2(0, 0), rD = rC;
        if (beg < end) {
            int2 r = csr[beg];
            aA = __int_as_float(r.y);
            GLOAD(va0, va1, va2, va3, r.x);
        }
        if (beg + 1 < end) rC = csr[beg + 1];
        if (beg + 2 < end) rD = csr[beg + 2];
        __syncthreads();  // eweb4 ready
        const float4* ep = u.eweb4 + qt * 17;

        f32x2 accv[16];
        GINIT(o0, o1, o2, o3);

        // 1-deep x pipeline + distance-2 csr prefetch (R6-proven codegen):
        // record for edge e+1 is RESIDENT when its GLOAD issues; csr never on the chain.
        int e = beg;
        while (e + 1 < end) {
            GPROC(va0, va1, va2, va3, aA);   // waits on this edge's x only
            aA = __int_as_float(rC.y);
            GLOAD(va0, va1, va2, va3, rC.x); // rC resident -> issue immediately
            rC = rD;                         // rD in flight since last iter (cheap partial wait)
            int i3 = min(e + 3, end - 1);    // unconditional clamped (no branch-merge waitcnt)
            rD = csr[i3];
            ++e;
        }
        if (e < end) GPROC(va0, va1, va2, va3, aA);

        // packed cvt + uint2 stores (2-way bank aliasing only = free)
        uint2* Ar2 = (uint2*)&A16[row * LDA + c0];
#pragma unroll
        for (int k = 0; k < 8; ++k) {
            Ar2[k] = make_uint2(cvt2_bf(accv[2 * k].x, accv[2 * k].y),
                                cvt2_bf(accv[2 * k + 1].x, accv[2 * k + 1].y));
        }
        // no barrier: rows [16wv,16wv+16) are written and read by the same wave
    } else {
        // layer 0 (din=5): 4 threads/row split the edge list; register partials
        const float* xinf = (const float*)xin_v;
        int row = tid >> 2, qt = tid & 3;
        int node = node0 + row;
        {
            float w[INDIM], b[INDIM], acc[INDIM];
#pragma unroll
            for (int j = 0; j < INDIM; ++j) {
                w[j] = ew[j];
                b[j] = eb[j];
                acc[j] = 0.f;
            }
            int beg = row_ptr[node], end = row_ptr[node + 1];
            int2 r;
            if (beg + qt < end) r = csr[beg + qt];
            for (int e = beg + qt; e < end; e += 4) {
                int2 rn = (e + 4 < end) ? csr[e + 4] : r;
                float a = __int_as_float(r.y);
#pragma unroll
                for (int j = 0; j < INDIM; ++j)
                    acc[j] += fmaxf(fmaf(a, w[j], xinf[r.x * INDIM + j] + b[j]), 0.f);
                r = rn;
            }
#pragma unroll
            for (int j = 0; j < INDIM; ++j) u.part[row][qt][j] = acc[j];
        }
        __syncthreads();
        if (tid < NPBLK) {
#pragma unroll
            for (int j = 0; j < INDIM; ++j) {
                float v = xinf[(node0 + tid) * INDIM + j] + u.part[tid][0][j] + u.part[tid][1][j] +
                          u.part[tid][2][j] + u.part[tid][3][j];
                A16[tid * LDA + j] = cvt1_bf(v);
            }
#pragma unroll
            for (int j = INDIM; j < 32; ++j) A16[tid * LDA + j] = 0;
        }
        __syncthreads();  // rows written by tid<64 -> cross-wave
    }

    // ---- MFMA MLP (wave-local rows) ----
    int wv = tid >> 6, lane = tid & 63;
    int mrow = lane & 15, q = lane >> 4;
    int arow = wv * 16 + mrow;

    const short8* w1p = (const short8*)w1h;
    const short8* w2p = (const short8*)w2h;

    f32x4 acc2[8];
#pragma unroll
    for (int t = 0; t < 8; ++t) acc2[t] = (f32x4){0.f, 0.f, 0.f, 0.f};
    constexpr int KS1 = KP1 / 32;
#pragma unroll
    for (int ks = 0; ks < KS1; ++ks) {
        short8 bh[8];
#pragma unroll
        for (int t = 0; t < 8; ++t) bh[t] = w1p[((size_t)t * KS1 + ks) * 64 + lane];
        short8 ah = *(const short8*)&A16[arow * LDA + ks * 32 + q * 8];
#pragma unroll
        for (int t = 0; t < 8; ++t)
            acc2[t] = __builtin_amdgcn_mfma_f32_16x16x32_bf16(ah, bh[t], acc2[t], 0, 0, 0);
    }
    // t1 = relu(acc + b1) -> bf16 A (wave-local rows)
    {
        float b1v[8];
#pragma unroll
        for (int t = 0; t < 8; ++t) b1v[t] = b1[t * 16 + mrow];
#pragma unroll
        for (int t = 0; t < 8; ++t)
#pragma unroll
            for (int r = 0; r < 4; ++r) {
                int rrow = wv * 16 + q * 4 + r;
                int col = t * 16 + mrow;
                A16[rrow * LDA + col] = cvt1_bf(fmaxf(acc2[t][r] + b1v[t], 0.f));
            }
    }

    // GEMM2 (K = 128); A reads wave-local
#pragma unroll
    for (int t = 0; t < 8; ++t) acc2[t] = (f32x4){0.f, 0.f, 0.f, 0.f};
#pragma unroll
    for (int ks = 0; ks < 4; ++ks) {
        short8 bh[8];
#pragma unroll
        for (int t = 0; t < 8; ++t) bh[t] = w2p[((size_t)t * 4 + ks) * 64 + lane];
        short8 ah = *(const short8*)&A16[arow * LDA + ks * 32 + q * 8];
#pragma unroll
        for (int t = 0; t < 8; ++t)
            acc2[t] = __builtin_amdgcn_mfma_f32_16x16x32_bf16(ah, bh[t], acc2[t], 0, 0, 0);
    }

    // ---- LayerNorm in registers (rows live in 16-lane groups) ----
    float s4[4] = {0.f, 0.f, 0.f, 0.f}, q4[4] = {0.f, 0.f, 0.f, 0.f};
    {
        float b2v[8];
#pragma unroll
        for (int t = 0; t < 8; ++t) b2v[t] = b2[t * 16 + mrow];
#pragma unroll
        for (int t = 0; t < 8; ++t)
#pragma unroll
            for (int r = 0; r < 4; ++r) {
                float v = acc2[t][r] + b2v[t];
                acc2[t][r] = v;
                s4[r] += v;
                q4[r] += v * v;
            }
    }
#pragma unroll
    for (int m = 1; m <= 8; m <<= 1) {
#pragma unroll
        for (int r = 0; r < 4; ++r) {
            s4[r] += __shfl_xor(s4[r], m, 64);
            q4[r] += __shfl_xor(q4[r], m, 64);
        }
    }
    float mu[4], inv[4];
#pragma unroll
    for (int r = 0; r < 4; ++r) {
        mu[r] = s4[r] * (1.f / HDIM);
        float var = q4[r] * (1.f / HDIM) - mu[r] * mu[r];
        inv[r] = rsqrtf(var + LN_EPS);
    }
    float gv[8], btv[8];
#pragma unroll
    for (int t = 0; t < 8; ++t) {
        gv[t] = g[t * 16 + mrow];
        btv[t] = bt[t * 16 + mrow];
    }

    // LN result -> LDS (wave-local row writes; no pre-barrier needed)
#pragma unroll
    for (int t = 0; t < 8; ++t)
#pragma unroll
        for (int r = 0; r < 4; ++r) {
            int rrow = wv * 16 + q * 4 + r;
            int col = t * 16 + mrow;
            float o = fmaxf((acc2[t][r] - mu[r]) * inv[r] * gv[t] + btv[t], 0.f);
            A16[rrow * LDA + col] = cvt1_bf(o);
        }
    __syncthreads();  // epilogue reads all rows (cross-wave)

    if (!POOL) {
        // coalesced copy-out: wave inst covers 256 contiguous bytes (4 full lines)
        unsigned* xo = (unsigned*)xout;
#pragma unroll
        for (int i = 0; i < 16; ++i) {
            int idx = tid + 256 * i;       // 4096 = 64 rows x 64 words
            int row = idx >> 6, w = idx & 63;
            xo[(size_t)(node0 + row) * 64 + w] = ((const unsigned*)&A16[row * LDA])[w];
        }
    } else {
        if (tid < 128) {
            int col = tid;
            float accp = 0.f;
            int cur = bidx[0];
            for (int r = 0; r < NPBLK; ++r) {
                int gi = bidx[r];
                if (gi != cur) {
                    unsafeAtomicAdd(&pool[cur * HDIM + col], accp);
                    accp = 0.f;
                    cur = gi;
                }
                accp += bf2f(A16[r * LDA + col]);
            }
            unsafeAtomicAdd(&pool[cur * HDIM + col], accp);
        } else if (tid == 255) {
            int cur = bidx[0], c = 0;
            for (int r = 0; r < NPBLK; ++r) {
                if (bidx[r] != cur) {
                    atomicAdd(&cnt[cur], c);
                    c = 0;
                    cur = bidx[r];
                }
                ++c;
            }
            atomicAdd(&cnt[cur], c);
        }
    }
}

__global__ void pool_final(const float* __restrict__ pool, const int* __restrict__ cnt,
                           float* __restrict__ out) {
    int g = blockIdx.x, j = threadIdx.x;
    float add = pool[g * HDIM + j];
    float c = (float)max(cnt[g], 1);
    out[g * (2 * HDIM) + j] = add / c;
    out[g * (2 * HDIM) + HDIM + j] = add;
}

extern "C" void kernel_launch(void* const* d_in, const int* in_sizes, int n_in,
                              void* d_out, int out_size, void* d_ws, size_t ws_size,
                              hipStream_t stream) {
    const float* x_in = (const float*)d_in[0];
    const int* ei = (const int*)d_in[1];
    const float* ea = (const float*)d_in[2];
    const int* batch = (const int*)d_in[3];
    const float* P[24];
    for (int i = 0; i < 24; ++i) P[i] = (const float*)d_in[4 + i];
    // per layer l (base 8l): 0=ew 1=eb 2=w1 3=b1 4=w2 5=b2 6=g 7=bt

    unsigned short* x_a = (unsigned short*)d_ws;                 // N*128 bf16
    unsigned short* x_b = x_a + (size_t)N_NODES * HDIM;          // N*128 bf16
    float* pool = (float*)(x_b + (size_t)N_NODES * HDIM);        // G*128 (zeroed in scanA)
    int* cnt = (int*)(pool + N_GRAPHS * HDIM);                   // G    (zeroed in scanA)
    int* deg = cnt + N_GRAPHS;                                   // N    (memset)
    int* cursor = deg + N_NODES;                                 // N    (zeroed in scanC)
    int* row_ptr = cursor + N_NODES;                             // N+1
    int* bsums = row_ptr + N_NODES + 1;                          // 256
    int* gbnd = bsums + 256;                                     // 128 (G+1 used)
    int* perm = gbnd + 128;                                      // N
    int* iperm = perm + N_NODES;                                 // N
    int* degp = iperm + N_NODES;                                 // N
    int* batchp = degp + N_NODES;                                // N
    float* xp = (float*)(batchp + N_NODES);                      // N*5 f32 (permuted input)
    int2* csr = (int2*)(((uintptr_t)(xp + (size_t)N_NODES * INDIM) + 15) & ~(uintptr_t)15);
    short* wp = (short*)(((uintptr_t)(csr + N_EDGES) + 15) & ~(uintptr_t)15);
    float* out = (float*)d_out;

    short *w1h[3], *w2h[3];
    for (int l = 0; l < 3; ++l) {
        w1h[l] = wp + (size_t)l * 32768;
        w2h[l] = w1h[l] + 16384;
    }

    // ---- memset: deg only (pool/cnt zeroed in scanA, cursor in scanC) ----
    hipMemsetAsync(deg, 0, N_NODES * sizeof(int), stream);

    // ---- degree histogram + degree-sorted (within-graph) permutation ----
    hist_kernel<<<(N_EDGES + 255) / 256, 256, 0, stream>>>(ei, deg);
    gbounds<<<1, 128, 0, stream>>>(batch, gbnd);
    gsort<<<N_GRAPHS, 256, 0, stream>>>(deg, gbnd, perm, iperm);
    permute_kernel<<<(N_NODES + 255) / 256, 256, 0, stream>>>(perm, deg, batch, x_in,
                                                              degp, batchp, xp);

    // ---- CSR build in permuted space ----
    scan_phaseA<<<SCAN_BLOCKS, 256, 0, stream>>>(degp, bsums, (int*)pool);
    scan_phaseB<<<1, 256, 0, stream>>>(bsums, row_ptr);
    scan_phaseC<<<SCAN_BLOCKS, 256, 0, stream>>>(degp, bsums, row_ptr, cursor);

    // ---- fused scatter (permuted) + weight packing ----
    scatter_pack<<<SCATTER_BLOCKS + 336, 256, 0, stream>>>(
        ei, ea, row_ptr, cursor, csr, iperm,
        P[2], w1h[0], P[4], w2h[0],
        P[10], w1h[1], P[12], w2h[1],
        P[18], w1h[2], P[20], w2h[2]);

    // ---- fused layers (permuted node space throughout) ----
    layer_fused<32, false><<<N_NODES / NPBLK, 256, 0, stream>>>(
        xp, row_ptr, csr, P[0], P[1],
        w1h[0], P[3], w2h[0], P[5], P[6], P[7], x_a, nullptr, nullptr, nullptr);
    layer_fused<128, false><<<N_NODES / NPBLK, 256, 0, stream>>>(
        x_a, row_ptr, csr, P[8], P[9],
        w1h[1], P[11], w2h[1], P[13], P[14], P[15], x_b, nullptr, nullptr, nullptr);
    layer_fused<128, true><<<N_NODES / NPBLK, 256, 0, stream>>>(
        x_b, row_ptr, csr, P[16], P[17],
        w1h[2], P[19], w2h[2], P[21], P[22], P[23], nullptr, batchp, pool, cnt);

    pool_final<<<N_GRAPHS, HDIM, 0, stream>>>(pool, cnt, out);
}